// Round 1
// baseline (339.350 us; speedup 1.0000x reference)
//
#include <hip/hip_runtime.h>

#define T_TOK 2048
#define H_DIM 1024
#define I_DIM 2048

typedef short short8 __attribute__((ext_vector_type(8)));
typedef float floatx4 __attribute__((ext_vector_type(4)));
typedef unsigned int uintx4 __attribute__((ext_vector_type(4)));

__device__ __forceinline__ unsigned short f2bf(float f) {
  unsigned int u = __builtin_bit_cast(unsigned int, f);
  u += 0x7FFFu + ((u >> 16) & 1u);
  return (unsigned short)(u >> 16);
}
__device__ __forceinline__ unsigned int packbf2(float lo, float hi) {
  return (unsigned int)f2bf(lo) | ((unsigned int)f2bf(hi) << 16);
}

// ---------------------------------------------------------------- gate
__global__ __launch_bounds__(256) void gate_kernel(
    const float* __restrict__ x, const float* __restrict__ gw,
    unsigned short* __restrict__ xb, int* __restrict__ cnt,
    int4* __restrict__ rec, float2* __restrict__ wrec)
{
  int t = blockIdx.x;
  int tid = threadIdx.x;
  const float* xr = x + (size_t)t * H_DIM;
  float xv[4];
#pragma unroll
  for (int j = 0; j < 4; ++j) {
    int h = tid + j * 256;
    xv[j] = xr[h];
    xb[(size_t)t * H_DIM + h] = f2bf(xv[j]);
  }
  float p[8];
#pragma unroll
  for (int e = 0; e < 8; ++e) {
    const float* g = gw + e * H_DIM;
    float s = 0.f;
#pragma unroll
    for (int j = 0; j < 4; ++j) s += xv[j] * g[tid + j * 256];
    p[e] = s;
  }
  __shared__ float red[8][4];
  int lane = tid & 63, wv = tid >> 6;
#pragma unroll
  for (int e = 0; e < 8; ++e) {
    float s = p[e];
#pragma unroll
    for (int off = 32; off > 0; off >>= 1) s += __shfl_down(s, off);
    if (lane == 0) red[e][wv] = s;
  }
  __syncthreads();
  if (tid == 0) {
    float sc[8], pr[8];
    float m = -1e30f;
#pragma unroll
    for (int e = 0; e < 8; ++e) {
      sc[e] = red[e][0] + red[e][1] + red[e][2] + red[e][3];
      m = fmaxf(m, sc[e]);
    }
    float Z = 0.f;
#pragma unroll
    for (int e = 0; e < 8; ++e) { pr[e] = __expf(sc[e] - m); Z += pr[e]; }
#pragma unroll
    for (int e = 0; e < 8; ++e) pr[e] /= Z;
    int i0 = 0;
#pragma unroll
    for (int e = 1; e < 8; ++e) if (pr[e] > pr[i0]) i0 = e;
    int i1 = (i0 == 0) ? 1 : 0;
#pragma unroll
    for (int e = 0; e < 8; ++e) if (e != i0 && pr[e] > pr[i1]) i1 = e;
    float w0 = pr[i0], w1 = pr[i1];
    float s2 = w0 + w1 + 1e-20f;
    w0 /= s2; w1 /= s2;
    int p0 = atomicAdd(&cnt[i0], 1);
    int p1 = atomicAdd(&cnt[i1], 1);
    rec[t] = make_int4(i0, i1, p0, p1);
    wrec[t] = make_float2(w0, w1);
  }
}

// ---------------------------------------------------------------- scatter
__global__ __launch_bounds__(256) void scatter_kernel(
    const int* __restrict__ cnt, const int4* __restrict__ rec,
    const float2* __restrict__ wrec, int* __restrict__ tok, float* __restrict__ wgt)
{
  int t = blockIdx.x * 256 + threadIdx.x;
  if (t >= T_TOK) return;
  int bases[8];
  int b = 0;
#pragma unroll
  for (int e = 0; e < 8; ++e) { bases[e] = b; b += cnt[e]; }
  int4 r = rec[t];
  float2 w = wrec[t];
  int s0 = bases[r.x] + r.z;
  int s1 = bases[r.y] + r.w;
  tok[s0] = t; wgt[s0] = w.x;
  tok[s1] = t; wgt[s1] = w.y;
  tok[b + t] = t; wgt[b + t] = 1.0f;   // shared expert slots
}

// ---------------------------------------------------------------- up GEMM
// tile: 128 rows x 64 cols, BK=32, 4 waves (2x2), both w1 and w3 accumulated.
__global__ __launch_bounds__(256) void ffn_up(
    const unsigned short* __restrict__ xb,
    const float* __restrict__ w1, const float* __restrict__ w3,
    const float* __restrict__ sw1, const float* __restrict__ sw3,
    const int* __restrict__ cnt, const int* __restrict__ tok,
    unsigned short* __restrict__ act)
{
  int z = blockIdx.z;
  int base = 0, nrows;
  {
    int b = 0;
#pragma unroll
    for (int e = 0; e < 8; ++e) { if (e < z || z == 8) b += cnt[e]; }
    base = b;
    nrows = (z == 8) ? T_TOK : cnt[z];
  }
  int row0 = blockIdx.y * 128;
  if (row0 >= nrows) return;
  int col0 = blockIdx.x * 64;
  const float* W1 = (z < 8) ? (w1 + (size_t)z * H_DIM * I_DIM) : sw1;
  const float* W3 = (z < 8) ? (w3 + (size_t)z * H_DIM * I_DIM) : sw3;

  __shared__ unsigned short Alds[128 * 40];       // 32 k + 8 pad per row
  __shared__ unsigned int Blds[2][64 * 20];       // [n][k-pairs], 16 used + 4 pad

  int tid = threadIdx.x;
  int lane = tid & 63;
  int g = lane >> 4;
  int l16 = lane & 15;
  int wv = tid >> 6;
  int wr = wv >> 1, wc = wv & 1;

  // A staging assignment
  int arow = tid & 127;
  int ah = tid >> 7;                               // 0/1: which 16-elem k-half
  int grow = row0 + arow;
  int tkn = tok[base + (grow < nrows ? grow : 0)];
  const unsigned short* aglob = xb + (size_t)tkn * H_DIM + ah * 16;
  unsigned short* aldsw = Alds + arow * 40 + ah * 16;

  // B staging assignment
  int bk = (tid >> 4) * 2;                         // even k row 0..30
  int bn0 = (tid & 15) * 4;
  const float* b1g = W1 + (size_t)bk * I_DIM + col0 + bn0;
  const float* b3g = W3 + (size_t)bk * I_DIM + col0 + bn0;
  int qq = bk >> 1;

  floatx4 acc1[4][2], acc3[4][2];
#pragma unroll
  for (int m = 0; m < 4; ++m)
#pragma unroll
    for (int nn = 0; nn < 2; ++nn) { acc1[m][nn] = (floatx4)0.f; acc3[m][nn] = (floatx4)0.f; }

  for (int ks = 0; ks < H_DIM / 32; ++ks) {
    uintx4 a0 = *(const uintx4*)(aglob);
    uintx4 a1 = *(const uintx4*)(aglob + 8);
    aglob += 32;
    floatx4 p10 = *(const floatx4*)(b1g);
    floatx4 p11 = *(const floatx4*)(b1g + I_DIM);
    floatx4 p30 = *(const floatx4*)(b3g);
    floatx4 p31 = *(const floatx4*)(b3g + I_DIM);
    b1g += 32 * I_DIM; b3g += 32 * I_DIM;

    __syncthreads();
    *(uintx4*)(aldsw) = a0;
    *(uintx4*)(aldsw + 8) = a1;
    Blds[0][(bn0 + 0) * 20 + qq] = packbf2(p10.x, p11.x);
    Blds[0][(bn0 + 1) * 20 + qq] = packbf2(p10.y, p11.y);
    Blds[0][(bn0 + 2) * 20 + qq] = packbf2(p10.z, p11.z);
    Blds[0][(bn0 + 3) * 20 + qq] = packbf2(p10.w, p11.w);
    Blds[1][(bn0 + 0) * 20 + qq] = packbf2(p30.x, p31.x);
    Blds[1][(bn0 + 1) * 20 + qq] = packbf2(p30.y, p31.y);
    Blds[1][(bn0 + 2) * 20 + qq] = packbf2(p30.z, p31.z);
    Blds[1][(bn0 + 3) * 20 + qq] = packbf2(p30.w, p31.w);
    __syncthreads();

    short8 af[4];
#pragma unroll
    for (int m = 0; m < 4; ++m)
      af[m] = *(const short8*)(Alds + (wr * 64 + m * 16 + l16) * 40 + g * 8);
#pragma unroll
    for (int nn = 0; nn < 2; ++nn) {
      int ncol = wc * 32 + nn * 16 + l16;
      short8 bf1 = *(const short8*)(&Blds[0][ncol * 20 + g * 4]);
      short8 bf3 = *(const short8*)(&Blds[1][ncol * 20 + g * 4]);
#pragma unroll
      for (int m = 0; m < 4; ++m) {
        acc1[m][nn] = __builtin_amdgcn_mfma_f32_16x16x32_bf16(af[m], bf1, acc1[m][nn], 0, 0, 0);
        acc3[m][nn] = __builtin_amdgcn_mfma_f32_16x16x32_bf16(af[m], bf3, acc3[m][nn], 0, 0, 0);
      }
    }
  }

#pragma unroll
  for (int m = 0; m < 4; ++m) {
    int rl = wr * 64 + m * 16 + g * 4;
#pragma unroll
    for (int nn = 0; nn < 2; ++nn) {
      int col = col0 + wc * 32 + nn * 16 + l16;
#pragma unroll
      for (int r = 0; r < 4; ++r) {
        int row = rl + r;
        if (row0 + row < nrows) {
          float h1 = acc1[m][nn][r], h3 = acc3[m][nn][r];
          float a = h1 / (1.0f + __expf(-h1)) * h3;
          act[(size_t)(base + row0 + row) * I_DIM + col] = f2bf(a);
        }
      }
    }
  }
}

// ---------------------------------------------------------------- down GEMM
__global__ __launch_bounds__(256) void ffn_down(
    const unsigned short* __restrict__ act,
    const float* __restrict__ w2, const float* __restrict__ sw2,
    const int* __restrict__ cnt, const int* __restrict__ tok,
    const float* __restrict__ wgt, float* __restrict__ out)
{
  int z = blockIdx.z;
  int base = 0, nrows;
  {
    int b = 0;
#pragma unroll
    for (int e = 0; e < 8; ++e) { if (e < z || z == 8) b += cnt[e]; }
    base = b;
    nrows = (z == 8) ? T_TOK : cnt[z];
  }
  int row0 = blockIdx.y * 128;
  if (row0 >= nrows) return;
  int col0 = blockIdx.x * 64;
  const float* W2 = (z < 8) ? (w2 + (size_t)z * I_DIM * H_DIM) : sw2;

  __shared__ unsigned short Alds[128 * 40];
  __shared__ unsigned int Blds[64 * 20];

  int tid = threadIdx.x;
  int lane = tid & 63;
  int g = lane >> 4;
  int l16 = lane & 15;
  int wv = tid >> 6;
  int wr = wv >> 1, wc = wv & 1;

  int arow = tid & 127;
  int ah = tid >> 7;
  int grow = row0 + arow;
  int asrc = grow < nrows ? grow : (nrows - 1);
  const unsigned short* aglob = act + (size_t)(base + asrc) * I_DIM + ah * 16;
  unsigned short* aldsw = Alds + arow * 40 + ah * 16;

  int bk = (tid >> 4) * 2;
  int bn0 = (tid & 15) * 4;
  const float* bg = W2 + (size_t)bk * H_DIM + col0 + bn0;
  int qq = bk >> 1;

  floatx4 acc[4][2];
#pragma unroll
  for (int m = 0; m < 4; ++m)
#pragma unroll
    for (int nn = 0; nn < 2; ++nn) acc[m][nn] = (floatx4)0.f;

  for (int ks = 0; ks < I_DIM / 32; ++ks) {
    uintx4 a0 = *(const uintx4*)(aglob);
    uintx4 a1 = *(const uintx4*)(aglob + 8);
    aglob += 32;
    floatx4 p0 = *(const floatx4*)(bg);
    floatx4 p1 = *(const floatx4*)(bg + H_DIM);
    bg += 32 * H_DIM;

    __syncthreads();
    *(uintx4*)(aldsw) = a0;
    *(uintx4*)(aldsw + 8) = a1;
    Blds[(bn0 + 0) * 20 + qq] = packbf2(p0.x, p1.x);
    Blds[(bn0 + 1) * 20 + qq] = packbf2(p0.y, p1.y);
    Blds[(bn0 + 2) * 20 + qq] = packbf2(p0.z, p1.z);
    Blds[(bn0 + 3) * 20 + qq] = packbf2(p0.w, p1.w);
    __syncthreads();

    short8 af[4];
#pragma unroll
    for (int m = 0; m < 4; ++m)
      af[m] = *(const short8*)(Alds + (wr * 64 + m * 16 + l16) * 40 + g * 8);
#pragma unroll
    for (int nn = 0; nn < 2; ++nn) {
      int ncol = wc * 32 + nn * 16 + l16;
      short8 bfr = *(const short8*)(&Blds[ncol * 20 + g * 4]);
#pragma unroll
      for (int m = 0; m < 4; ++m)
        acc[m][nn] = __builtin_amdgcn_mfma_f32_16x16x32_bf16(af[m], bfr, acc[m][nn], 0, 0, 0);
    }
  }

#pragma unroll
  for (int m = 0; m < 4; ++m) {
    int rl = wr * 64 + m * 16 + g * 4;
    int tk4[4]; float wg4[4]; bool ok4[4];
#pragma unroll
    for (int r = 0; r < 4; ++r) {
      int row = rl + r;
      ok4[r] = (row0 + row) < nrows;
      int slot = base + row0 + (ok4[r] ? row : 0);
      tk4[r] = tok[slot];
      wg4[r] = wgt[slot];
    }
#pragma unroll
    for (int nn = 0; nn < 2; ++nn) {
      int col = col0 + wc * 32 + nn * 16 + l16;
#pragma unroll
      for (int r = 0; r < 4; ++r) {
        if (ok4[r])
          atomicAdd(&out[(size_t)tk4[r] * H_DIM + col], acc[m][nn][r] * wg4[r]);
      }
    }
  }
}

// ---------------------------------------------------------------- launch
extern "C" void kernel_launch(void* const* d_in, const int* in_sizes, int n_in,
                              void* d_out, int out_size, void* d_ws, size_t ws_size,
                              hipStream_t stream) {
  const float* x   = (const float*)d_in[0];
  const float* gw  = (const float*)d_in[1];
  const float* w1  = (const float*)d_in[2];
  const float* w2  = (const float*)d_in[3];
  const float* w3  = (const float*)d_in[4];
  const float* sw1 = (const float*)d_in[5];
  const float* sw2 = (const float*)d_in[6];
  const float* sw3 = (const float*)d_in[7];
  float* out = (float*)d_out;

  char* ws = (char*)d_ws;
  int*            cnt  = (int*)ws;                           // 64 B
  int4*           rec  = (int4*)(ws + 1024);                 // 32 KB
  float2*         wrec = (float2*)(ws + (64 << 10));         // 16 KB
  int*            tok  = (int*)(ws + (128 << 10));           // 24 KB
  float*          wgt  = (float*)(ws + (192 << 10));         // 24 KB
  unsigned short* xb   = (unsigned short*)(ws + (1 << 20));  // 4 MB
  unsigned short* act  = (unsigned short*)(ws + (8 << 20));  // 24 MB

  hipMemsetAsync(cnt, 0, 64, stream);
  hipMemsetAsync(out, 0, (size_t)T_TOK * H_DIM * sizeof(float), stream);

  gate_kernel<<<T_TOK, 256, 0, stream>>>(x, gw, xb, cnt, rec, wrec);
  scatter_kernel<<<T_TOK / 256, 256, 0, stream>>>(cnt, rec, wrec, tok, wgt);
  ffn_up<<<dim3(I_DIM / 64, 16, 9), 256, 0, stream>>>(xb, w1, w3, sw1, sw3, cnt, tok, act);
  ffn_down<<<dim3(H_DIM / 64, 16, 9), 256, 0, stream>>>(act, w2, sw2, cnt, tok, wgt, out);
}

// Round 2
// 281.392 us; speedup vs baseline: 1.2060x; 1.2060x over previous
//
#include <hip/hip_runtime.h>

#define T_TOK 2048
#define H_DIM 1024
#define I_DIM 2048
#define SHBASE 4096          // T*K expert slots; shared slots follow
#define NSLOT 6144

typedef short short8 __attribute__((ext_vector_type(8)));
typedef float floatx4 __attribute__((ext_vector_type(4)));

__device__ __forceinline__ unsigned short f2bf(float f) {
  unsigned int u = __builtin_bit_cast(unsigned int, f);
  u += 0x7FFFu + ((u >> 16) & 1u);
  return (unsigned short)(u >> 16);
}
__device__ __forceinline__ unsigned int packbf2(float lo, float hi) {
  return (unsigned int)f2bf(lo) | ((unsigned int)f2bf(hi) << 16);
}
__device__ __forceinline__ void gl16(const void* g, void* l) {
  __builtin_amdgcn_global_load_lds(
      (const __attribute__((address_space(1))) unsigned int*)g,
      (__attribute__((address_space(3))) unsigned int*)l, 16, 0, 0);
}

// ---------------------------------------------------------------- gate
__global__ __launch_bounds__(256) void gate_kernel(
    const float* __restrict__ x, const float* __restrict__ gw,
    unsigned short* __restrict__ xb, int* __restrict__ cnt,
    int4* __restrict__ rec, float2* __restrict__ wrec)
{
  int t = blockIdx.x;
  int tid = threadIdx.x;
  const float* xr = x + (size_t)t * H_DIM;
  float xv[4];
#pragma unroll
  for (int j = 0; j < 4; ++j) {
    int h = tid + j * 256;
    xv[j] = xr[h];
    xb[(size_t)t * H_DIM + h] = f2bf(xv[j]);
  }
  float p[8];
#pragma unroll
  for (int e = 0; e < 8; ++e) {
    const float* gptr = gw + e * H_DIM;
    float s = 0.f;
#pragma unroll
    for (int j = 0; j < 4; ++j) s += xv[j] * gptr[tid + j * 256];
    p[e] = s;
  }
  __shared__ float red[8][4];
  int lane = tid & 63, wv = tid >> 6;
#pragma unroll
  for (int e = 0; e < 8; ++e) {
    float s = p[e];
#pragma unroll
    for (int off = 32; off > 0; off >>= 1) s += __shfl_down(s, off);
    if (lane == 0) red[e][wv] = s;
  }
  __syncthreads();
  if (tid == 0) {
    float sc[8], pr[8];
    float m = -1e30f;
#pragma unroll
    for (int e = 0; e < 8; ++e) {
      sc[e] = red[e][0] + red[e][1] + red[e][2] + red[e][3];
      m = fmaxf(m, sc[e]);
    }
    float Z = 0.f;
#pragma unroll
    for (int e = 0; e < 8; ++e) { pr[e] = __expf(sc[e] - m); Z += pr[e]; }
#pragma unroll
    for (int e = 0; e < 8; ++e) pr[e] /= Z;
    int i0 = 0;
#pragma unroll
    for (int e = 1; e < 8; ++e) if (pr[e] > pr[i0]) i0 = e;
    int i1 = (i0 == 0) ? 1 : 0;
#pragma unroll
    for (int e = 0; e < 8; ++e) if (e != i0 && pr[e] > pr[i1]) i1 = e;
    float w0 = pr[i0], w1 = pr[i1];
    float s2 = w0 + w1 + 1e-20f;
    w0 /= s2; w1 /= s2;
    int p0 = atomicAdd(&cnt[i0], 1);
    int p1 = atomicAdd(&cnt[i1], 1);
    rec[t] = make_int4(i0, i1, p0, p1);
    wrec[t] = make_float2(w0, w1);
  }
}

// ---------------------------------------------------------------- scatter
__global__ __launch_bounds__(256) void scatter_kernel(
    const int* __restrict__ cnt, const int4* __restrict__ rec,
    int* __restrict__ tok, int2* __restrict__ slots)
{
  int t = blockIdx.x * 256 + threadIdx.x;
  if (t >= T_TOK) return;
  int bases[8];
  int b = 0;
#pragma unroll
  for (int e = 0; e < 8; ++e) { bases[e] = b; b += cnt[e]; }
  int4 r = rec[t];
  int s0 = bases[r.x] + r.z;
  int s1 = bases[r.y] + r.w;
  tok[s0] = t;
  tok[s1] = t;
  tok[SHBASE + t] = t;        // shared expert slot
  slots[t] = make_int2(s0, s1);
}

// ---------------------------------------------------------------- up GEMM
// 128 rows x 64 cols, BK=64, 4 waves (2x2), w1+w3 in one pass, 2-phase pipeline.
__global__ __launch_bounds__(256) void ffn_up(
    const unsigned short* __restrict__ xb,
    const float* __restrict__ w1, const float* __restrict__ w3,
    const float* __restrict__ sw1, const float* __restrict__ sw3,
    const int* __restrict__ cnt, const int* __restrict__ tok,
    unsigned short* __restrict__ act)
{
  int z = blockIdx.z;
  int base = 0, nrows;
  {
    int b = 0;
#pragma unroll
    for (int e = 0; e < 8; ++e) if (e < z || z == 8) b += cnt[e];
    base = b;
    nrows = (z == 8) ? T_TOK : cnt[z];
  }
  int row0 = blockIdx.y * 128;
  if (row0 >= nrows) return;
  int col0 = blockIdx.x * 64;
  const float* W1 = (z < 8) ? (w1 + (size_t)z * H_DIM * I_DIM) : sw1;
  const float* W3 = (z < 8) ? (w3 + (size_t)z * H_DIM * I_DIM) : sw3;

  __shared__ unsigned short Alds[2][128 * 64];   // 16KB x2, XOR-swizzled chunks
  __shared__ unsigned int  Blds[2][2][64 * 32];  // [buf][mat][col*32 + swz]  8KB each

  const int tid = threadIdx.x;
  const int lane = tid & 63, wv = tid >> 6;
  const int l16 = lane & 15, g = lane >> 4;
  const int wr = wv >> 1, wc = wv & 1;

  // A staging: wave wv covers rows [wv*32, wv*32+32), 4 gl16 per tile.
  // lane -> row i*8 + (lane>>3), LDS chunk (lane&7); source chunk XOR row&7.
  const int lsub = lane >> 3;
  const int schunk = (lane & 7) ^ lsub;
  const unsigned short* asrc[4];
#pragma unroll
  for (int i = 0; i < 4; ++i) {
    int lrow = wv * 32 + i * 8 + lsub;
    int grow = row0 + lrow;
    if (grow >= nrows) grow = nrows - 1;
    asrc[i] = xb + (size_t)tok[base + grow] * H_DIM + schunk * 8;
  }

  // B staging: thread -> k rows 4u..4u+3, cols c4..c4+3 (coalesced 16B loads).
  const int u = tid >> 4;
  const int c4 = (tid & 15) * 4;
  const float* b1p = W1 + (size_t)(4 * u) * I_DIM + col0 + c4;
  const float* b3p = W3 + (size_t)(4 * u) * I_DIM + col0 + c4;
  int widx[4];
#pragma unroll
  for (int j = 0; j < 4; ++j) {
    int col = c4 + j;
    widx[j] = col * 32 + ((((u >> 1) ^ ((col ^ (col >> 3)) & 7)) << 2) + 2 * (u & 1));
  }

  floatx4 acc1[4][2], acc3[4][2];
#pragma unroll
  for (int m = 0; m < 4; ++m)
#pragma unroll
    for (int nn = 0; nn < 2; ++nn) { acc1[m][nn] = (floatx4)0.f; acc3[m][nn] = (floatx4)0.f; }

  floatx4 r1[4], r3[4];

  auto stage_a = [&](int buf, int ks) {
#pragma unroll
    for (int i = 0; i < 4; ++i)
      gl16(asrc[i] + ks * 64, &Alds[buf][(wv * 32 + i * 8) * 64]);
  };
  auto load_b = [&](int ks) {
    const float* p1 = b1p + (size_t)ks * 64 * I_DIM;
    const float* p3 = b3p + (size_t)ks * 64 * I_DIM;
#pragma unroll
    for (int j = 0; j < 4; ++j) {
      r1[j] = *(const floatx4*)(p1 + (size_t)j * I_DIM);
      r3[j] = *(const floatx4*)(p3 + (size_t)j * I_DIM);
    }
  };
  auto write_b = [&](int buf) {
#pragma unroll
    for (int j = 0; j < 4; ++j) {
      uint2 v1, v3;
      v1.x = packbf2(r1[0][j], r1[1][j]); v1.y = packbf2(r1[2][j], r1[3][j]);
      v3.x = packbf2(r3[0][j], r3[1][j]); v3.y = packbf2(r3[2][j], r3[3][j]);
      *(uint2*)&Blds[buf][0][widx[j]] = v1;
      *(uint2*)&Blds[buf][1][widx[j]] = v3;
    }
  };
  auto compute = [&](int buf) {
#pragma unroll
    for (int kk = 0; kk < 2; ++kk) {
      short8 af[4];
#pragma unroll
      for (int m = 0; m < 4; ++m) {
        int row = wr * 64 + m * 16 + l16;
        af[m] = *(const short8*)&Alds[buf][row * 64 + (((kk * 4 + g) ^ (l16 & 7)) * 8)];
      }
#pragma unroll
      for (int nn = 0; nn < 2; ++nn) {
        int col = wc * 32 + nn * 16 + l16;
        int bidx = col * 32 + (((kk * 4 + g) ^ ((col ^ (col >> 3)) & 7)) << 2);
        short8 bf1 = *(const short8*)&Blds[buf][0][bidx];
        short8 bf3 = *(const short8*)&Blds[buf][1][bidx];
#pragma unroll
        for (int m = 0; m < 4; ++m) {
          acc1[m][nn] = __builtin_amdgcn_mfma_f32_16x16x32_bf16(af[m], bf1, acc1[m][nn], 0, 0, 0);
          acc3[m][nn] = __builtin_amdgcn_mfma_f32_16x16x32_bf16(af[m], bf3, acc3[m][nn], 0, 0, 0);
        }
      }
    }
  };

  stage_a(0, 0);
  load_b(0);
  for (int ks = 0; ks < H_DIM / 64; ++ks) {
    int cur = ks & 1;
    write_b(cur);
    __syncthreads();                 // drains vmcnt(0): A[cur] in LDS, B writes visible
    if (ks < H_DIM / 64 - 1) {       // prefetch next tile; stays in flight through MFMA
      stage_a(cur ^ 1, ks + 1);
      load_b(ks + 1);
    }
    compute(cur);
  }

#pragma unroll
  for (int m = 0; m < 4; ++m) {
    int rl = wr * 64 + m * 16 + g * 4;
#pragma unroll
    for (int nn = 0; nn < 2; ++nn) {
      int col = col0 + wc * 32 + nn * 16 + l16;
#pragma unroll
      for (int r = 0; r < 4; ++r) {
        int row = rl + r;
        if (row0 + row < nrows) {
          float h1 = acc1[m][nn][r], h3 = acc3[m][nn][r];
          float a = h1 / (1.0f + __expf(-h1)) * h3;
          act[(size_t)(base + row0 + row) * I_DIM + col] = f2bf(a);
        }
      }
    }
  }
}

// ---------------------------------------------------------------- down GEMM
// 128 rows x 64 cols, BK=64, per-slot output (no atomics), 2-phase pipeline.
__global__ __launch_bounds__(256) void ffn_down(
    const unsigned short* __restrict__ act,
    const float* __restrict__ w2, const float* __restrict__ sw2,
    const int* __restrict__ cnt, float* __restrict__ yslot)
{
  int z = blockIdx.z;
  int base = 0, nrows;
  {
    int b = 0;
#pragma unroll
    for (int e = 0; e < 8; ++e) if (e < z || z == 8) b += cnt[e];
    base = b;
    nrows = (z == 8) ? T_TOK : cnt[z];
  }
  int row0 = blockIdx.y * 128;
  if (row0 >= nrows) return;
  int col0 = blockIdx.x * 64;
  const float* W2 = (z < 8) ? (w2 + (size_t)z * I_DIM * H_DIM) : sw2;

  __shared__ unsigned short Alds[2][128 * 64];
  __shared__ unsigned int  Blds[2][64 * 32];

  const int tid = threadIdx.x;
  const int lane = tid & 63, wv = tid >> 6;
  const int l16 = lane & 15, g = lane >> 4;
  const int wr = wv >> 1, wc = wv & 1;

  const int lsub = lane >> 3;
  const int schunk = (lane & 7) ^ lsub;
  const unsigned short* asrc[4];
#pragma unroll
  for (int i = 0; i < 4; ++i) {
    int lrow = wv * 32 + i * 8 + lsub;
    int grow = row0 + lrow;
    if (grow >= nrows) grow = nrows - 1;
    asrc[i] = act + (size_t)(base + grow) * I_DIM + schunk * 8;
  }

  const int u = tid >> 4;
  const int c4 = (tid & 15) * 4;
  const float* bp = W2 + (size_t)(4 * u) * H_DIM + col0 + c4;
  int widx[4];
#pragma unroll
  for (int j = 0; j < 4; ++j) {
    int col = c4 + j;
    widx[j] = col * 32 + ((((u >> 1) ^ ((col ^ (col >> 3)) & 7)) << 2) + 2 * (u & 1));
  }

  floatx4 acc[4][2];
#pragma unroll
  for (int m = 0; m < 4; ++m)
#pragma unroll
    for (int nn = 0; nn < 2; ++nn) acc[m][nn] = (floatx4)0.f;

  floatx4 rb[4];

  auto stage_a = [&](int buf, int ks) {
#pragma unroll
    for (int i = 0; i < 4; ++i)
      gl16(asrc[i] + ks * 64, &Alds[buf][(wv * 32 + i * 8) * 64]);
  };
  auto load_b = [&](int ks) {
    const float* p = bp + (size_t)ks * 64 * H_DIM;
#pragma unroll
    for (int j = 0; j < 4; ++j)
      rb[j] = *(const floatx4*)(p + (size_t)j * H_DIM);
  };
  auto write_b = [&](int buf) {
#pragma unroll
    for (int j = 0; j < 4; ++j) {
      uint2 v;
      v.x = packbf2(rb[0][j], rb[1][j]); v.y = packbf2(rb[2][j], rb[3][j]);
      *(uint2*)&Blds[buf][widx[j]] = v;
    }
  };
  auto compute = [&](int buf) {
#pragma unroll
    for (int kk = 0; kk < 2; ++kk) {
      short8 af[4];
#pragma unroll
      for (int m = 0; m < 4; ++m) {
        int row = wr * 64 + m * 16 + l16;
        af[m] = *(const short8*)&Alds[buf][row * 64 + (((kk * 4 + g) ^ (l16 & 7)) * 8)];
      }
#pragma unroll
      for (int nn = 0; nn < 2; ++nn) {
        int col = wc * 32 + nn * 16 + l16;
        int bidx = col * 32 + (((kk * 4 + g) ^ ((col ^ (col >> 3)) & 7)) << 2);
        short8 bfr = *(const short8*)&Blds[buf][bidx];
#pragma unroll
        for (int m = 0; m < 4; ++m)
          acc[m][nn] = __builtin_amdgcn_mfma_f32_16x16x32_bf16(af[m], bfr, acc[m][nn], 0, 0, 0);
      }
    }
  };

  stage_a(0, 0);
  load_b(0);
  for (int ks = 0; ks < I_DIM / 64; ++ks) {
    int cur = ks & 1;
    write_b(cur);
    __syncthreads();
    if (ks < I_DIM / 64 - 1) {
      stage_a(cur ^ 1, ks + 1);
      load_b(ks + 1);
    }
    compute(cur);
  }

#pragma unroll
  for (int m = 0; m < 4; ++m) {
    int rl = wr * 64 + m * 16 + g * 4;
#pragma unroll
    for (int nn = 0; nn < 2; ++nn) {
      int col = col0 + wc * 32 + nn * 16 + l16;
#pragma unroll
      for (int r = 0; r < 4; ++r) {
        int row = rl + r;
        if (row0 + row < nrows)
          yslot[(size_t)(base + row0 + row) * H_DIM + col] = acc[m][nn][r];
      }
    }
  }
}

// ---------------------------------------------------------------- combine
__global__ __launch_bounds__(256) void combine_kernel(
    const float* __restrict__ y, const int2* __restrict__ slots,
    const float2* __restrict__ wrec, float* __restrict__ out)
{
  int t = blockIdx.x;
  int h = threadIdx.x * 4;
  int2 s = slots[t];
  float2 w = wrec[t];
  floatx4 a = *(const floatx4*)&y[(size_t)s.x * H_DIM + h];
  floatx4 b = *(const floatx4*)&y[(size_t)s.y * H_DIM + h];
  floatx4 c = *(const floatx4*)&y[(size_t)(SHBASE + t) * H_DIM + h];
  floatx4 o = a * w.x + b * w.y + c;
  *(floatx4*)&out[(size_t)t * H_DIM + h] = o;
}

// ---------------------------------------------------------------- launch
extern "C" void kernel_launch(void* const* d_in, const int* in_sizes, int n_in,
                              void* d_out, int out_size, void* d_ws, size_t ws_size,
                              hipStream_t stream) {
  const float* x   = (const float*)d_in[0];
  const float* gw  = (const float*)d_in[1];
  const float* w1  = (const float*)d_in[2];
  const float* w2  = (const float*)d_in[3];
  const float* w3  = (const float*)d_in[4];
  const float* sw1 = (const float*)d_in[5];
  const float* sw2 = (const float*)d_in[6];
  const float* sw3 = (const float*)d_in[7];
  float* out = (float*)d_out;

  char* ws = (char*)d_ws;
  int*            cnt   = (int*)ws;                           // 64 B
  int4*           rec   = (int4*)(ws + 1024);                 // 32 KB
  float2*         wrec  = (float2*)(ws + (64 << 10));         // 16 KB
  int*            tok   = (int*)(ws + (128 << 10));           // 24 KB
  int2*           slots = (int2*)(ws + (192 << 10));          // 16 KB
  unsigned short* xb    = (unsigned short*)(ws + (1 << 20));  // 4 MB
  unsigned short* act   = (unsigned short*)(ws + (8 << 20));  // 25.2 MB
  float*          yslot = (float*)(ws + (40ull << 20));       // 25.2 MB

  hipMemsetAsync(cnt, 0, 64, stream);

  gate_kernel<<<T_TOK, 256, 0, stream>>>(x, gw, xb, cnt, rec, wrec);
  scatter_kernel<<<T_TOK / 256, 256, 0, stream>>>(cnt, rec, tok, slots);
  ffn_up<<<dim3(I_DIM / 64, 16, 9), 256, 0, stream>>>(xb, w1, w3, sw1, sw3, cnt, tok, act);
  ffn_down<<<dim3(H_DIM / 64, 16, 9), 256, 0, stream>>>(act, w2, sw2, cnt, yslot);
  combine_kernel<<<T_TOK, 256, 0, stream>>>(yslot, slots, wrec, out);
}

// Round 3
// 262.075 us; speedup vs baseline: 1.2949x; 1.0737x over previous
//
#include <hip/hip_runtime.h>

#define T_TOK 2048
#define H_DIM 1024
#define I_DIM 2048
#define SHBASE 4096              // T*K expert slots; shared slots follow
#define KN_PANEL (1024 * 2048)   // elements per weight panel (both shapes)

typedef short short8 __attribute__((ext_vector_type(8)));
typedef float floatx4 __attribute__((ext_vector_type(4)));

__device__ __forceinline__ unsigned short f2bf(float f) {
  unsigned int u = __builtin_bit_cast(unsigned int, f);
  u += 0x7FFFu + ((u >> 16) & 1u);
  return (unsigned short)(u >> 16);
}
__device__ __forceinline__ unsigned int packbf2(float lo, float hi) {
  return (unsigned int)f2bf(lo) | ((unsigned int)f2bf(hi) << 16);
}
__device__ __forceinline__ float bf2f(unsigned short u) {
  return __builtin_bit_cast(float, (unsigned int)u << 16);
}
__device__ __forceinline__ void gl16(const void* g, void* l) {
  __builtin_amdgcn_global_load_lds(
      (const __attribute__((address_space(1))) unsigned int*)g,
      (__attribute__((address_space(3))) unsigned int*)l, 16, 0, 0);
}
__device__ __forceinline__ int fsw(int r) { return (r ^ (r >> 2)) & 3; }

// ---------------------------------------------------------------- weight conv
// fp32 [K][N] row-major -> bf16 image of 8KB tiles [nt][kt], tile = 128 cols x 32 k.
// chunk q in 0..511: c=q>>2, o'=q&3, holds k-oct o = o'^fsw(c) of col c (8 bf16, k-major).
__device__ __forceinline__ void conv_tile(const float* __restrict__ src,
                                          unsigned short* __restrict__ dst,
                                          int N, int nt, int kt) {
  int t = threadIdx.x;
#pragma unroll
  for (int half = 0; half < 2; ++half) {
    int q = t + half * 256;
    int c = q >> 2;
    int o = (q & 3) ^ fsw(c);
    const float* p = src + (size_t)(kt * 32 + o * 8) * N + nt * 128 + c;
    float v[8];
#pragma unroll
    for (int j = 0; j < 8; ++j) v[j] = p[(size_t)j * N];
    uint4 w;
    w.x = packbf2(v[0], v[1]); w.y = packbf2(v[2], v[3]);
    w.z = packbf2(v[4], v[5]); w.w = packbf2(v[6], v[7]);
    *(uint4*)(dst + (size_t)q * 8) = w;
  }
}

__global__ __launch_bounds__(256) void conv_up(
    const float* __restrict__ w1, const float* __restrict__ w3,
    const float* __restrict__ sw1, const float* __restrict__ sw3,
    unsigned short* __restrict__ img) {
  int z = blockIdx.z;
  const float* src = (z < 8)  ? w1 + (size_t)z * KN_PANEL
                   : (z < 16) ? w3 + (size_t)(z - 8) * KN_PANEL
                   : (z == 16) ? sw1 : sw3;
  unsigned short* dst = img + (size_t)z * KN_PANEL
      + ((size_t)blockIdx.x * gridDim.y + blockIdx.y) * 4096;
  conv_tile(src, dst, I_DIM, blockIdx.x, blockIdx.y);
}

__global__ __launch_bounds__(256) void conv_dn(
    const float* __restrict__ w2, const float* __restrict__ sw2,
    unsigned short* __restrict__ img) {
  int z = blockIdx.z;
  const float* src = (z < 8) ? w2 + (size_t)z * KN_PANEL : sw2;
  unsigned short* dst = img + (size_t)z * KN_PANEL
      + ((size_t)blockIdx.x * gridDim.y + blockIdx.y) * 4096;
  conv_tile(src, dst, H_DIM, blockIdx.x, blockIdx.y);
}

// ---------------------------------------------------------------- gate
__global__ __launch_bounds__(256) void gate_kernel(
    const float* __restrict__ x, const float* __restrict__ gw,
    unsigned short* __restrict__ xb, int* __restrict__ cnt,
    int4* __restrict__ rec, float2* __restrict__ wrec)
{
  int t = blockIdx.x;
  int tid = threadIdx.x;
  const float* xr = x + (size_t)t * H_DIM;
  float xv[4];
#pragma unroll
  for (int j = 0; j < 4; ++j) {
    int h = tid + j * 256;
    xv[j] = xr[h];
    xb[(size_t)t * H_DIM + h] = f2bf(xv[j]);
  }
  float p[8];
#pragma unroll
  for (int e = 0; e < 8; ++e) {
    const float* gptr = gw + e * H_DIM;
    float s = 0.f;
#pragma unroll
    for (int j = 0; j < 4; ++j) s += xv[j] * gptr[tid + j * 256];
    p[e] = s;
  }
  __shared__ float red[8][4];
  int lane = tid & 63, wv = tid >> 6;
#pragma unroll
  for (int e = 0; e < 8; ++e) {
    float s = p[e];
#pragma unroll
    for (int off = 32; off > 0; off >>= 1) s += __shfl_down(s, off);
    if (lane == 0) red[e][wv] = s;
  }
  __syncthreads();
  if (tid == 0) {
    float sc[8], pr[8];
    float m = -1e30f;
#pragma unroll
    for (int e = 0; e < 8; ++e) {
      sc[e] = red[e][0] + red[e][1] + red[e][2] + red[e][3];
      m = fmaxf(m, sc[e]);
    }
    float Z = 0.f;
#pragma unroll
    for (int e = 0; e < 8; ++e) { pr[e] = __expf(sc[e] - m); Z += pr[e]; }
#pragma unroll
    for (int e = 0; e < 8; ++e) pr[e] /= Z;
    int i0 = 0;
#pragma unroll
    for (int e = 1; e < 8; ++e) if (pr[e] > pr[i0]) i0 = e;
    int i1 = (i0 == 0) ? 1 : 0;
#pragma unroll
    for (int e = 0; e < 8; ++e) if (e != i0 && pr[e] > pr[i1]) i1 = e;
    float w0 = pr[i0], w1 = pr[i1];
    float s2 = w0 + w1 + 1e-20f;
    w0 /= s2; w1 /= s2;
    int p0 = atomicAdd(&cnt[i0], 1);
    int p1 = atomicAdd(&cnt[i1], 1);
    rec[t] = make_int4(i0, i1, p0, p1);
    wrec[t] = make_float2(w0, w1);
  }
}

// ---------------------------------------------------------------- scatter
__global__ __launch_bounds__(256) void scatter_kernel(
    const int* __restrict__ cnt, const int4* __restrict__ rec,
    int* __restrict__ tok, int2* __restrict__ slots)
{
  int t = blockIdx.x * 256 + threadIdx.x;
  if (t >= T_TOK) return;
  int bases[8];
  int b = 0;
#pragma unroll
  for (int e = 0; e < 8; ++e) { bases[e] = b; b += cnt[e]; }
  int4 r = rec[t];
  int s0 = bases[r.x] + r.z;
  int s1 = bases[r.y] + r.w;
  tok[s0] = t;
  tok[s1] = t;
  tok[SHBASE + t] = t;
  slots[t] = make_int2(s0, s1);
}

// ---------------------------------------------------------------- up GEMM
// 128r x 128c tile, BK=32, 512 thr (8 waves 2Mx4N), w1+w3 fused, all-DMA staging.
__global__ __launch_bounds__(512, 4) void ffn_up(
    const unsigned short* __restrict__ xb,
    const unsigned short* __restrict__ imgUp,
    const int* __restrict__ cnt, const int* __restrict__ tok,
    unsigned short* __restrict__ act)
{
  int z = blockIdx.z;
  int base = 0;
#pragma unroll
  for (int e = 0; e < 8; ++e) if (e < z || z == 8) base += cnt[e];
  int nrows = (z == 8) ? T_TOK : cnt[z];
  int row0 = blockIdx.y * 128;
  if (row0 >= nrows) return;
  int nt = blockIdx.x;
  int p1 = (z < 8) ? z : 16;
  int p3 = (z < 8) ? (8 + z) : 17;

  __shared__ unsigned short A[2][4096];
  __shared__ unsigned short B1[2][4096];
  __shared__ unsigned short B3[2][4096];

  const int tid = threadIdx.x;
  const int lane = tid & 63, wv = tid >> 6;
  const int l16 = lane & 15, g = lane >> 4;
  const int wr = wv >> 2, wc = wv & 3;

  // staging sources (chunk q = tid)
  const int arow = tid >> 2;
  const int aoct = (tid & 3) ^ fsw(arow);
  int grow = row0 + arow;
  if (grow >= nrows) grow = nrows - 1;
  const unsigned short* pA = xb + (size_t)tok[base + grow] * H_DIM + aoct * 8;
  const unsigned short* pB1 = imgUp + (size_t)p1 * KN_PANEL + (size_t)nt * 32 * 4096 + tid * 8;
  const unsigned short* pB3 = imgUp + (size_t)p3 * KN_PANEL + (size_t)nt * 32 * 4096 + tid * 8;

  // fragment chunk offsets (ushort units)
  int ach[4], bch[2];
#pragma unroll
  for (int m = 0; m < 4; ++m) {
    int r = wr * 64 + m * 16 + l16;
    ach[m] = (r * 4 + (g ^ fsw(r))) * 8;
  }
#pragma unroll
  for (int n = 0; n < 2; ++n) {
    int c = wc * 32 + n * 16 + l16;
    bch[n] = (c * 4 + (g ^ fsw(c))) * 8;
  }

  floatx4 acc1[4][2], acc3[4][2];
#pragma unroll
  for (int m = 0; m < 4; ++m)
#pragma unroll
    for (int n = 0; n < 2; ++n) { acc1[m][n] = (floatx4)0.f; acc3[m][n] = (floatx4)0.f; }

  auto stage = [&](int buf, int ks) {
    gl16(pA + ks * 32, &A[buf][wv * 512]);
    gl16(pB1 + (size_t)ks * 4096, &B1[buf][wv * 512]);
    gl16(pB3 + (size_t)ks * 4096, &B3[buf][wv * 512]);
  };

  stage(0, 0);
  for (int ks = 0; ks < H_DIM / 32; ++ks) {
    int cur = ks & 1;
    __syncthreads();                       // own-vmcnt drained -> buf cur complete
    if (ks + 1 < H_DIM / 32) stage(cur ^ 1, ks + 1);   // in flight through MFMA
    short8 af[4];
#pragma unroll
    for (int m = 0; m < 4; ++m) af[m] = *(const short8*)&A[cur][ach[m]];
#pragma unroll
    for (int n = 0; n < 2; ++n) {
      short8 b1 = *(const short8*)&B1[cur][bch[n]];
      short8 b3 = *(const short8*)&B3[cur][bch[n]];
#pragma unroll
      for (int m = 0; m < 4; ++m) {
        acc1[m][n] = __builtin_amdgcn_mfma_f32_16x16x32_bf16(af[m], b1, acc1[m][n], 0, 0, 0);
        acc3[m][n] = __builtin_amdgcn_mfma_f32_16x16x32_bf16(af[m], b3, acc3[m][n], 0, 0, 0);
      }
    }
  }

#pragma unroll
  for (int m = 0; m < 4; ++m) {
    int rl = wr * 64 + m * 16 + g * 4;
#pragma unroll
    for (int n = 0; n < 2; ++n) {
      int col = nt * 128 + wc * 32 + n * 16 + l16;
#pragma unroll
      for (int r = 0; r < 4; ++r) {
        int row = rl + r;
        if (row0 + row < nrows) {
          float h1 = acc1[m][n][r], h3 = acc3[m][n][r];
          float a = h1 / (1.0f + __expf(-h1)) * h3;
          act[(size_t)(base + row0 + row) * I_DIM + col] = f2bf(a);
        }
      }
    }
  }
}

// ---------------------------------------------------------------- down GEMM
__global__ __launch_bounds__(512, 4) void ffn_down(
    const unsigned short* __restrict__ act,
    const unsigned short* __restrict__ imgDn,
    const int* __restrict__ cnt, unsigned short* __restrict__ yslot)
{
  int z = blockIdx.z;
  int base = 0;
#pragma unroll
  for (int e = 0; e < 8; ++e) if (e < z || z == 8) base += cnt[e];
  int nrows = (z == 8) ? T_TOK : cnt[z];
  int row0 = blockIdx.y * 128;
  if (row0 >= nrows) return;
  int nt = blockIdx.x;

  __shared__ unsigned short A[2][4096];
  __shared__ unsigned short B[2][4096];

  const int tid = threadIdx.x;
  const int lane = tid & 63, wv = tid >> 6;
  const int l16 = lane & 15, g = lane >> 4;
  const int wr = wv >> 2, wc = wv & 3;

  const int arow = tid >> 2;
  const int aoct = (tid & 3) ^ fsw(arow);
  int grow = row0 + arow;
  if (grow >= nrows) grow = nrows - 1;
  const unsigned short* pA = act + (size_t)(base + grow) * I_DIM + aoct * 8;
  const unsigned short* pB = imgDn + (size_t)z * KN_PANEL + (size_t)nt * 64 * 4096 + tid * 8;

  int ach[4], bch[2];
#pragma unroll
  for (int m = 0; m < 4; ++m) {
    int r = wr * 64 + m * 16 + l16;
    ach[m] = (r * 4 + (g ^ fsw(r))) * 8;
  }
#pragma unroll
  for (int n = 0; n < 2; ++n) {
    int c = wc * 32 + n * 16 + l16;
    bch[n] = (c * 4 + (g ^ fsw(c))) * 8;
  }

  floatx4 acc[4][2];
#pragma unroll
  for (int m = 0; m < 4; ++m)
#pragma unroll
    for (int n = 0; n < 2; ++n) acc[m][n] = (floatx4)0.f;

  auto stage = [&](int buf, int ks) {
    gl16(pA + ks * 32, &A[buf][wv * 512]);
    gl16(pB + (size_t)ks * 4096, &B[buf][wv * 512]);
  };

  stage(0, 0);
  for (int ks = 0; ks < I_DIM / 32; ++ks) {
    int cur = ks & 1;
    __syncthreads();
    if (ks + 1 < I_DIM / 32) stage(cur ^ 1, ks + 1);
    short8 af[4];
#pragma unroll
    for (int m = 0; m < 4; ++m) af[m] = *(const short8*)&A[cur][ach[m]];
#pragma unroll
    for (int n = 0; n < 2; ++n) {
      short8 bfr = *(const short8*)&B[cur][bch[n]];
#pragma unroll
      for (int m = 0; m < 4; ++m)
        acc[m][n] = __builtin_amdgcn_mfma_f32_16x16x32_bf16(af[m], bfr, acc[m][n], 0, 0, 0);
    }
  }

#pragma unroll
  for (int m = 0; m < 4; ++m) {
    int rl = wr * 64 + m * 16 + g * 4;
#pragma unroll
    for (int n = 0; n < 2; ++n) {
      int col = nt * 128 + wc * 32 + n * 16 + l16;
#pragma unroll
      for (int r = 0; r < 4; ++r) {
        int row = rl + r;
        if (row0 + row < nrows)
          yslot[(size_t)(base + row0 + row) * H_DIM + col] = f2bf(acc[m][n][r]);
      }
    }
  }
}

// ---------------------------------------------------------------- combine
__global__ __launch_bounds__(256) void combine_kernel(
    const unsigned short* __restrict__ y, const int2* __restrict__ slots,
    const float2* __restrict__ wrec, float* __restrict__ out)
{
  int t = blockIdx.x;
  int h = threadIdx.x * 4;
  int2 s = slots[t];
  float2 w = wrec[t];
  ushort4 a = *(const ushort4*)&y[(size_t)s.x * H_DIM + h];
  ushort4 b = *(const ushort4*)&y[(size_t)s.y * H_DIM + h];
  ushort4 c = *(const ushort4*)&y[(size_t)(SHBASE + t) * H_DIM + h];
  floatx4 o;
  o[0] = bf2f(a.x) * w.x + bf2f(b.x) * w.y + bf2f(c.x);
  o[1] = bf2f(a.y) * w.x + bf2f(b.y) * w.y + bf2f(c.y);
  o[2] = bf2f(a.z) * w.x + bf2f(b.z) * w.y + bf2f(c.z);
  o[3] = bf2f(a.w) * w.x + bf2f(b.w) * w.y + bf2f(c.w);
  *(floatx4*)&out[(size_t)t * H_DIM + h] = o;
}

// ---------------------------------------------------------------- launch
extern "C" void kernel_launch(void* const* d_in, const int* in_sizes, int n_in,
                              void* d_out, int out_size, void* d_ws, size_t ws_size,
                              hipStream_t stream) {
  const float* x   = (const float*)d_in[0];
  const float* gw  = (const float*)d_in[1];
  const float* w1  = (const float*)d_in[2];
  const float* w2  = (const float*)d_in[3];
  const float* w3  = (const float*)d_in[4];
  const float* sw1 = (const float*)d_in[5];
  const float* sw2 = (const float*)d_in[6];
  const float* sw3 = (const float*)d_in[7];
  float* out = (float*)d_out;

  char* ws = (char*)d_ws;
  int*            cnt   = (int*)ws;                            // 64 B
  int4*           rec   = (int4*)(ws + 1024);                  // 32 KB
  float2*         wrec  = (float2*)(ws + (64 << 10));          // 16 KB
  int*            tok   = (int*)(ws + (128 << 10));            // 24 KB
  int2*           slots = (int2*)(ws + (192 << 10));           // 16 KB
  unsigned short* xb    = (unsigned short*)(ws + (1 << 20));   // 4 MB
  unsigned short* act   = (unsigned short*)(ws + (8ull << 20));   // 24 MB
  unsigned short* yslot = (unsigned short*)(ws + (32ull << 20));  // 12 MB
  unsigned short* img   = (unsigned short*)(ws + (48ull << 20));  // 72 MB (dn aliases)

  hipMemsetAsync(cnt, 0, 64, stream);

  conv_up<<<dim3(I_DIM / 128, H_DIM / 32, 18), 256, 0, stream>>>(w1, w3, sw1, sw3, img);
  gate_kernel<<<T_TOK, 256, 0, stream>>>(x, gw, xb, cnt, rec, wrec);
  scatter_kernel<<<T_TOK / 256, 256, 0, stream>>>(cnt, rec, tok, slots);
  ffn_up<<<dim3(I_DIM / 128, 16, 9), 512, 0, stream>>>(xb, img, cnt, tok, act);
  conv_dn<<<dim3(H_DIM / 128, I_DIM / 32, 9), 256, 0, stream>>>(w2, sw2, img);
  ffn_down<<<dim3(H_DIM / 128, 16, 9), 512, 0, stream>>>(act, img, cnt, yslot);
  combine_kernel<<<T_TOK, 256, 0, stream>>>(yslot, slots, wrec, out);
}

// Round 4
// 240.024 us; speedup vs baseline: 1.4138x; 1.0919x over previous
//
#include <hip/hip_runtime.h>

#define T_TOK 2048
#define H_DIM 1024
#define I_DIM 2048
#define SHBASE 4096              // T*K expert slots; shared slots follow
#define KN_PANEL (1024 * 2048)   // elements per weight panel (both shapes)

typedef short short8 __attribute__((ext_vector_type(8)));
typedef float floatx4 __attribute__((ext_vector_type(4)));

#define WAITVM(N) asm volatile("s_waitcnt vmcnt(" #N ")" ::: "memory")

__device__ __forceinline__ unsigned short f2bf(float f) {
  unsigned int u = __builtin_bit_cast(unsigned int, f);
  u += 0x7FFFu + ((u >> 16) & 1u);
  return (unsigned short)(u >> 16);
}
__device__ __forceinline__ unsigned int packbf2(float lo, float hi) {
  return (unsigned int)f2bf(lo) | ((unsigned int)f2bf(hi) << 16);
}
__device__ __forceinline__ float bf2f(unsigned short u) {
  return __builtin_bit_cast(float, (unsigned int)u << 16);
}
__device__ __forceinline__ void gl16(const void* g, void* l) {
  __builtin_amdgcn_global_load_lds(
      (const __attribute__((address_space(1))) unsigned int*)g,
      (__attribute__((address_space(3))) unsigned int*)l, 16, 0, 0);
}

// Row-pair bank swizzle. Tile = 128 rows x 32 k (4 octs of 8 bf16) = 512 x 16B chunks.
// chunk(r,o) = (r>>1)*8 + ((o + 4*(r&1)) ^ ((r>>1)&7)).
// Fragment read (16 rows x 4 octs per wave): each 16-lane group covers all 8 bank
// slots exactly 2x -> conflict-free (2-way is free).
__device__ __forceinline__ int cidx(int r, int o) {
  int p = r >> 1;
  int s = o + ((r & 1) << 2);
  return p * 8 + (s ^ (p & 7));
}

// ---------------------------------------------------------------- weight conv
// fp32 [K][N] row-major -> bf16 image of 8KB tiles in cidx chunk order.
__device__ __forceinline__ void conv_tile(const float* __restrict__ src,
                                          unsigned short* __restrict__ dst,
                                          int N, int nt, int kt, int t) {
#pragma unroll
  for (int half = 0; half < 2; ++half) {
    int q = t + half * 256;
    int p = q >> 3, s = (q & 7) ^ (p & 7);
    int c = p * 2 + (s >> 2), o = s & 3;
    const float* pp = src + (size_t)(kt * 32 + o * 8) * N + nt * 128 + c;
    float v[8];
#pragma unroll
    for (int j = 0; j < 8; ++j) v[j] = pp[(size_t)j * N];
    uint4 w;
    w.x = packbf2(v[0], v[1]); w.y = packbf2(v[2], v[3]);
    w.z = packbf2(v[4], v[5]); w.w = packbf2(v[6], v[7]);
    *(uint4*)(dst + (size_t)q * 8) = w;
  }
}

// ---------------------------------------------------------------- prep: conv_up + gate fused
__global__ __launch_bounds__(256) void prep_kernel(
    const float* __restrict__ x, const float* __restrict__ gw,
    const float* __restrict__ w1, const float* __restrict__ w3,
    const float* __restrict__ sw1, const float* __restrict__ sw3,
    unsigned short* __restrict__ img, unsigned short* __restrict__ xb,
    int* __restrict__ cnt, int4* __restrict__ rec, float2* __restrict__ wrec)
{
  __shared__ float red[8][4];
  int bid = blockIdx.x;
  int tid = threadIdx.x;
  if (bid < 9216) {                       // conv_up: 18 panels x 512 tiles
    int z = bid >> 9;
    int tile = bid & 511;                 // tile = nt*32 + kt
    const float* src = (z < 8)  ? w1 + (size_t)z * KN_PANEL
                     : (z < 16) ? w3 + (size_t)(z - 8) * KN_PANEL
                     : (z == 16) ? sw1 : sw3;
    unsigned short* dst = img + (size_t)z * KN_PANEL + (size_t)tile * 4096;
    conv_tile(src, dst, I_DIM, tile >> 5, tile & 31, tid);
    return;
  }
  // ------- gate
  int t = bid - 9216;
  const float* xr = x + (size_t)t * H_DIM;
  float xv[4];
#pragma unroll
  for (int j = 0; j < 4; ++j) {
    int h = tid + j * 256;
    xv[j] = xr[h];
    xb[(size_t)t * H_DIM + h] = f2bf(xv[j]);
  }
  float p[8];
#pragma unroll
  for (int e = 0; e < 8; ++e) {
    const float* gptr = gw + e * H_DIM;
    float s = 0.f;
#pragma unroll
    for (int j = 0; j < 4; ++j) s += xv[j] * gptr[tid + j * 256];
    p[e] = s;
  }
  int lane = tid & 63, wv = tid >> 6;
#pragma unroll
  for (int e = 0; e < 8; ++e) {
    float s = p[e];
#pragma unroll
    for (int off = 32; off > 0; off >>= 1) s += __shfl_down(s, off);
    if (lane == 0) red[e][wv] = s;
  }
  __syncthreads();
  if (tid == 0) {
    float sc[8], pr[8];
    float m = -1e30f;
#pragma unroll
    for (int e = 0; e < 8; ++e) {
      sc[e] = red[e][0] + red[e][1] + red[e][2] + red[e][3];
      m = fmaxf(m, sc[e]);
    }
    float Z = 0.f;
#pragma unroll
    for (int e = 0; e < 8; ++e) { pr[e] = __expf(sc[e] - m); Z += pr[e]; }
#pragma unroll
    for (int e = 0; e < 8; ++e) pr[e] /= Z;
    int i0 = 0;
#pragma unroll
    for (int e = 1; e < 8; ++e) if (pr[e] > pr[i0]) i0 = e;
    int i1 = (i0 == 0) ? 1 : 0;
#pragma unroll
    for (int e = 0; e < 8; ++e) if (e != i0 && pr[e] > pr[i1]) i1 = e;
    float w0 = pr[i0], w1 = pr[i1];
    float s2 = w0 + w1 + 1e-20f;
    w0 /= s2; w1 /= s2;
    int p0 = atomicAdd(&cnt[i0], 1);
    int p1 = atomicAdd(&cnt[i1], 1);
    rec[t] = make_int4(i0, i1, p0, p1);
    wrec[t] = make_float2(w0, w1);
  }
}

__global__ __launch_bounds__(256) void conv_dn(
    const float* __restrict__ w2, const float* __restrict__ sw2,
    unsigned short* __restrict__ img) {
  int z = blockIdx.z;
  const float* src = (z < 8) ? w2 + (size_t)z * KN_PANEL : sw2;
  int tile = blockIdx.x * gridDim.y + blockIdx.y;   // nt*64 + kt
  unsigned short* dst = img + (size_t)z * KN_PANEL + (size_t)tile * 4096;
  conv_tile(src, dst, H_DIM, blockIdx.x, blockIdx.y, threadIdx.x);
}

// ---------------------------------------------------------------- scatter
__global__ __launch_bounds__(256) void scatter_kernel(
    const int* __restrict__ cnt, const int4* __restrict__ rec,
    int* __restrict__ tok, int2* __restrict__ slots)
{
  int t = blockIdx.x * 256 + threadIdx.x;
  if (t >= T_TOK) return;
  int bases[8];
  int b = 0;
#pragma unroll
  for (int e = 0; e < 8; ++e) { bases[e] = b; b += cnt[e]; }
  int4 r = rec[t];
  int s0 = bases[r.x] + r.z;
  int s1 = bases[r.y] + r.w;
  tok[s0] = t;
  tok[s1] = t;
  tok[SHBASE + t] = t;
  slots[t] = make_int2(s0, s1);
}

// ---------------------------------------------------------------- up GEMM
// 128r x 128c, BK=32, 8 waves (2Mx4N), w1+w3 fused, triple-buffer depth-2
// counted-vmcnt pipeline, all-DMA staging, swizzled LDS.
__global__ __launch_bounds__(512, 4) void ffn_up(
    const unsigned short* __restrict__ xb,
    const unsigned short* __restrict__ imgUp,
    const int* __restrict__ cnt, const int* __restrict__ tok,
    unsigned short* __restrict__ act)
{
  int z = blockIdx.z;
  int base = 0;
#pragma unroll
  for (int e = 0; e < 8; ++e) if (e < z || z == 8) base += cnt[e];
  int nrows = (z == 8) ? T_TOK : cnt[z];
  int row0 = blockIdx.y * 128;
  if (row0 >= nrows) return;
  int nt = blockIdx.x;
  int p1 = (z < 8) ? z : 16;
  int p3 = (z < 8) ? (8 + z) : 17;

  __shared__ unsigned short A[3][4096];
  __shared__ unsigned short B1[3][4096];
  __shared__ unsigned short B3[3][4096];

  const int tid = threadIdx.x;
  const int lane = tid & 63, wv = tid >> 6;
  const int l16 = lane & 15, g = lane >> 4;
  const int wr = wv >> 2, wc = wv & 3;

  // A staging: chunk q = tid; invert cidx to get (row, oct); source pre-swizzled.
  {
  }
  int qp = tid >> 3, qs = (tid & 7) ^ (qp & 7);
  int ar = qp * 2 + (qs >> 2), ao = qs & 3;
  int grow = row0 + ar;
  if (grow >= nrows) grow = nrows - 1;
  const unsigned short* pA = xb + (size_t)tok[base + grow] * H_DIM + ao * 8;
  const unsigned short* pB1 = imgUp + (size_t)p1 * KN_PANEL + (size_t)nt * 32 * 4096 + tid * 8;
  const unsigned short* pB3 = imgUp + (size_t)p3 * KN_PANEL + (size_t)nt * 32 * 4096 + tid * 8;

  int ach[4], bch[2];
#pragma unroll
  for (int m = 0; m < 4; ++m) ach[m] = cidx(wr * 64 + m * 16 + l16, g) * 8;
#pragma unroll
  for (int n = 0; n < 2; ++n) bch[n] = cidx(wc * 32 + n * 16 + l16, g) * 8;

  floatx4 acc1[4][2], acc3[4][2];
#pragma unroll
  for (int m = 0; m < 4; ++m)
#pragma unroll
    for (int n = 0; n < 2; ++n) { acc1[m][n] = (floatx4)0.f; acc3[m][n] = (floatx4)0.f; }

  auto stage = [&](int buf, int ks) {           // 3 VMEM ops
    gl16(pA + ks * 32, &A[buf][wv * 512]);
    gl16(pB1 + (size_t)ks * 4096, &B1[buf][wv * 512]);
    gl16(pB3 + (size_t)ks * 4096, &B3[buf][wv * 512]);
  };
  auto compute = [&](int buf) {
    short8 af[4];
#pragma unroll
    for (int m = 0; m < 4; ++m) af[m] = *(const short8*)&A[buf][ach[m]];
#pragma unroll
    for (int n = 0; n < 2; ++n) {
      short8 b1 = *(const short8*)&B1[buf][bch[n]];
      short8 b3 = *(const short8*)&B3[buf][bch[n]];
#pragma unroll
      for (int m = 0; m < 4; ++m) {
        acc1[m][n] = __builtin_amdgcn_mfma_f32_16x16x32_bf16(af[m], b1, acc1[m][n], 0, 0, 0);
        acc3[m][n] = __builtin_amdgcn_mfma_f32_16x16x32_bf16(af[m], b3, acc3[m][n], 0, 0, 0);
      }
    }
  };

  const int NT = H_DIM / 32;
  stage(0, 0); stage(1, 1);
  for (int ks = 0; ks < NT - 1; ++ks) {
    int cur = ks % 3;
    WAITVM(3);                       // stage(ks) done; stage(ks+1) still in flight
    __builtin_amdgcn_sched_barrier(0);
    __builtin_amdgcn_s_barrier();
    if (ks + 2 < NT) stage((ks + 2) % 3, ks + 2);
    __builtin_amdgcn_s_setprio(1);
    compute(cur);
    __builtin_amdgcn_s_setprio(0);
    __builtin_amdgcn_sched_barrier(0);
  }
  WAITVM(0);
  __builtin_amdgcn_sched_barrier(0);
  __builtin_amdgcn_s_barrier();
  compute((NT - 1) % 3);

#pragma unroll
  for (int m = 0; m < 4; ++m) {
    int rl = wr * 64 + m * 16 + g * 4;
#pragma unroll
    for (int n = 0; n < 2; ++n) {
      int col = nt * 128 + wc * 32 + n * 16 + l16;
#pragma unroll
      for (int r = 0; r < 4; ++r) {
        int row = rl + r;
        if (row0 + row < nrows) {
          float h1 = acc1[m][n][r], h3 = acc3[m][n][r];
          float a = h1 / (1.0f + __expf(-h1)) * h3;
          act[(size_t)(base + row0 + row) * I_DIM + col] = f2bf(a);
        }
      }
    }
  }
}

// ---------------------------------------------------------------- down GEMM
__global__ __launch_bounds__(512, 4) void ffn_down(
    const unsigned short* __restrict__ act,
    const unsigned short* __restrict__ imgDn,
    const int* __restrict__ cnt, unsigned short* __restrict__ yslot)
{
  int z = blockIdx.z;
  int base = 0;
#pragma unroll
  for (int e = 0; e < 8; ++e) if (e < z || z == 8) base += cnt[e];
  int nrows = (z == 8) ? T_TOK : cnt[z];
  int row0 = blockIdx.y * 128;
  if (row0 >= nrows) return;
  int nt = blockIdx.x;

  __shared__ unsigned short A[3][4096];
  __shared__ unsigned short B[3][4096];

  const int tid = threadIdx.x;
  const int lane = tid & 63, wv = tid >> 6;
  const int l16 = lane & 15, g = lane >> 4;
  const int wr = wv >> 2, wc = wv & 3;

  int qp = tid >> 3, qs = (tid & 7) ^ (qp & 7);
  int ar = qp * 2 + (qs >> 2), ao = qs & 3;
  int grow = row0 + ar;
  if (grow >= nrows) grow = nrows - 1;
  const unsigned short* pA = act + (size_t)(base + grow) * I_DIM + ao * 8;
  const unsigned short* pB = imgDn + (size_t)z * KN_PANEL + (size_t)nt * 64 * 4096 + tid * 8;

  int ach[4], bch[2];
#pragma unroll
  for (int m = 0; m < 4; ++m) ach[m] = cidx(wr * 64 + m * 16 + l16, g) * 8;
#pragma unroll
  for (int n = 0; n < 2; ++n) bch[n] = cidx(wc * 32 + n * 16 + l16, g) * 8;

  floatx4 acc[4][2];
#pragma unroll
  for (int m = 0; m < 4; ++m)
#pragma unroll
    for (int n = 0; n < 2; ++n) acc[m][n] = (floatx4)0.f;

  auto stage = [&](int buf, int ks) {           // 2 VMEM ops
    gl16(pA + ks * 32, &A[buf][wv * 512]);
    gl16(pB + (size_t)ks * 4096, &B[buf][wv * 512]);
  };
  auto compute = [&](int buf) {
    short8 af[4];
#pragma unroll
    for (int m = 0; m < 4; ++m) af[m] = *(const short8*)&A[buf][ach[m]];
#pragma unroll
    for (int n = 0; n < 2; ++n) {
      short8 bfr = *(const short8*)&B[buf][bch[n]];
#pragma unroll
      for (int m = 0; m < 4; ++m)
        acc[m][n] = __builtin_amdgcn_mfma_f32_16x16x32_bf16(af[m], bfr, acc[m][n], 0, 0, 0);
    }
  };

  const int NT = I_DIM / 32;
  stage(0, 0); stage(1, 1);
  for (int ks = 0; ks < NT - 1; ++ks) {
    int cur = ks % 3;
    WAITVM(2);
    __builtin_amdgcn_sched_barrier(0);
    __builtin_amdgcn_s_barrier();
    if (ks + 2 < NT) stage((ks + 2) % 3, ks + 2);
    __builtin_amdgcn_s_setprio(1);
    compute(cur);
    __builtin_amdgcn_s_setprio(0);
    __builtin_amdgcn_sched_barrier(0);
  }
  WAITVM(0);
  __builtin_amdgcn_sched_barrier(0);
  __builtin_amdgcn_s_barrier();
  compute((NT - 1) % 3);

#pragma unroll
  for (int m = 0; m < 4; ++m) {
    int rl = wr * 64 + m * 16 + g * 4;
#pragma unroll
    for (int n = 0; n < 2; ++n) {
      int col = nt * 128 + wc * 32 + n * 16 + l16;
#pragma unroll
      for (int r = 0; r < 4; ++r) {
        int row = rl + r;
        if (row0 + row < nrows)
          yslot[(size_t)(base + row0 + row) * H_DIM + col] = f2bf(acc[m][n][r]);
      }
    }
  }
}

// ---------------------------------------------------------------- combine
__global__ __launch_bounds__(256) void combine_kernel(
    const unsigned short* __restrict__ y, const int2* __restrict__ slots,
    const float2* __restrict__ wrec, float* __restrict__ out)
{
  int t = blockIdx.x;
  int h = threadIdx.x * 4;
  int2 s = slots[t];
  float2 w = wrec[t];
  ushort4 a = *(const ushort4*)&y[(size_t)s.x * H_DIM + h];
  ushort4 b = *(const ushort4*)&y[(size_t)s.y * H_DIM + h];
  ushort4 c = *(const ushort4*)&y[(size_t)(SHBASE + t) * H_DIM + h];
  floatx4 o;
  o[0] = bf2f(a.x) * w.x + bf2f(b.x) * w.y + bf2f(c.x);
  o[1] = bf2f(a.y) * w.x + bf2f(b.y) * w.y + bf2f(c.y);
  o[2] = bf2f(a.z) * w.x + bf2f(b.z) * w.y + bf2f(c.z);
  o[3] = bf2f(a.w) * w.x + bf2f(b.w) * w.y + bf2f(c.w);
  *(floatx4*)&out[(size_t)t * H_DIM + h] = o;
}

// ---------------------------------------------------------------- launch
extern "C" void kernel_launch(void* const* d_in, const int* in_sizes, int n_in,
                              void* d_out, int out_size, void* d_ws, size_t ws_size,
                              hipStream_t stream) {
  const float* x   = (const float*)d_in[0];
  const float* gw  = (const float*)d_in[1];
  const float* w1  = (const float*)d_in[2];
  const float* w2  = (const float*)d_in[3];
  const float* w3  = (const float*)d_in[4];
  const float* sw1 = (const float*)d_in[5];
  const float* sw2 = (const float*)d_in[6];
  const float* sw3 = (const float*)d_in[7];
  float* out = (float*)d_out;

  char* ws = (char*)d_ws;
  int*            cnt   = (int*)ws;                            // 64 B
  int4*           rec   = (int4*)(ws + 1024);                  // 32 KB
  float2*         wrec  = (float2*)(ws + (64 << 10));          // 16 KB
  int*            tok   = (int*)(ws + (128 << 10));            // 24 KB
  int2*           slots = (int2*)(ws + (192 << 10));           // 16 KB
  unsigned short* xb    = (unsigned short*)(ws + (1 << 20));   // 4 MB
  unsigned short* act   = (unsigned short*)(ws + (8ull << 20));   // 24 MB
  unsigned short* yslot = (unsigned short*)(ws + (32ull << 20));  // 12 MB
  unsigned short* img   = (unsigned short*)(ws + (48ull << 20));  // 72 MB (dn aliases)

  hipMemsetAsync(cnt, 0, 64, stream);

  prep_kernel<<<9216 + T_TOK, 256, 0, stream>>>(x, gw, w1, w3, sw1, sw3,
                                                img, xb, cnt, rec, wrec);
  scatter_kernel<<<T_TOK / 256, 256, 0, stream>>>(cnt, rec, tok, slots);
  ffn_up<<<dim3(I_DIM / 128, 16, 9), 512, 0, stream>>>(xb, img, cnt, tok, act);
  conv_dn<<<dim3(H_DIM / 128, I_DIM / 32, 9), 256, 0, stream>>>(w2, sw2, img);
  ffn_down<<<dim3(H_DIM / 128, 16, 9), 512, 0, stream>>>(act, img, cnt, yslot);
  combine_kernel<<<T_TOK, 256, 0, stream>>>(yslot, slots, wrec, out);
}